// Round 2
// baseline (1766.717 us; speedup 1.0000x reference)
//
#include <hip/hip_runtime.h>
#include <hip/hip_bf16.h>
#include <math.h>

#define BB 4096
#define TT 200
#define EE 64

// ws float layout:
//  [0,5120)          WkC = W1[64:128]-W1[128:192]   (64x80)
//  [5120,10240)      WqC = W1[0:64]+W1[128:192]     (64x80)
//  [10240,337920)    qW  = targets@WqC + b1         (B x 80)
//  [337920,1157120)  logits [T][B]
//  [1157120,1976320) scores [T][B]
//  -- big-ws path only --
//  [1976320,3614720) xg   [T][B] float2 {x.Wu1, x.Wr1}
//  [3614720,56043520) xc  [T][B][64] = x@Wc1 + bc
#define OFF_XG 1976320
#define OFF_XC 3614720
#define WS_NEED_BYTES ((size_t)(OFF_XC + (size_t)BB * TT * 64) * 4)

__device__ __forceinline__ float lane_bcast(float v, int l) {
    return __int_as_float(__builtin_amdgcn_readlane(__float_as_int(v), l));
}

// sum over all 64 lanes: 4 DPP row_ror adds (VALU, intra-row16) + 2 shfl levels
__device__ __forceinline__ float dpp_ror_add(float s, const int ctrl) {
    int t;
    switch (ctrl) {   // dpp_ctrl must be a literal constant
        case 8: t = __builtin_amdgcn_update_dpp(0, __float_as_int(s), 0x128, 0xF, 0xF, true); break;
        case 4: t = __builtin_amdgcn_update_dpp(0, __float_as_int(s), 0x124, 0xF, 0xF, true); break;
        case 2: t = __builtin_amdgcn_update_dpp(0, __float_as_int(s), 0x122, 0xF, 0xF, true); break;
        default: t = __builtin_amdgcn_update_dpp(0, __float_as_int(s), 0x121, 0xF, 0xF, true); break;
    }
    return s + __int_as_float(t);
}

__device__ __forceinline__ float wave_sum64(float v) {
    v = dpp_ror_add(v, 8);
    v = dpp_ror_add(v, 4);
    v = dpp_ror_add(v, 2);
    v = dpp_ror_add(v, 1);
    v += __shfl_xor(v, 16);
    v += __shfl_xor(v, 32);
    return v;
}

__global__ __launch_bounds__(256) void prep_kernel(const float* __restrict__ W1,
                                                   float* __restrict__ ws) {
    int idx = blockIdx.x * 256 + threadIdx.x;   // i*80+j, i<64
    if (idx >= 64 * 80) return;
    float wa = W1[idx];
    float wb = W1[64 * 80 + idx];
    float wc = W1[128 * 80 + idx];
    ws[idx]        = wb - wc;   // WkC
    ws[5120 + idx] = wa + wc;   // WqC
}

__global__ __launch_bounds__(256) void qw_kernel(const float* __restrict__ targets,
                                                 const float* __restrict__ b1,
                                                 const float* __restrict__ ws,
                                                 float* __restrict__ qW) {
    int idx = blockIdx.x * 256 + threadIdx.x;   // b*80+j
    int b = idx / 80;
    int j = idx - b * 80;
    const float* q  = targets + (size_t)b * 64;
    const float* Wq = ws + 5120;
    float s = b1[j];
#pragma unroll
    for (int i = 0; i < 64; i++) s = fmaf(q[i], Wq[i * 80 + j], s);
    qW[idx] = s;
}

// one thread per (b,t). Two-pass over the 80 layer-1 columns so the live
// accumulator set is h2[10] (persistent) + h1[10] (per pass) ~= 80 regs,
// fitting 128 VGPR without scratch spills (round-1 counters showed VGPR=80
// with ~160MB scratch re-read traffic from a spilled h1[20]).
__global__ __launch_bounds__(256, 4) void mlp_kernel(
    const float* __restrict__ gru, const float* __restrict__ targets,
    const float* __restrict__ W1, const float* __restrict__ W2,
    const float* __restrict__ b2, const float* __restrict__ Wf,
    const float* __restrict__ bf, const float* __restrict__ Wu,
    const float* __restrict__ Wr, const float* __restrict__ ws,
    float* __restrict__ logits, float* __restrict__ xg) {
    __shared__ float4 sWk[1280];   // [64][20 quads]
    __shared__ float4 sWp[1280];
    const float4* WkC = (const float4*)ws;              // 5120 floats
    const float4* Wp  = (const float4*)(W1 + 192 * 80); // last 64 rows of W1
    for (int i = threadIdx.x; i < 1280; i += 256) {
        sWk[i] = WkC[i];
        sWp[i] = Wp[i];
    }
    __syncthreads();

    int idx = blockIdx.x * 256 + threadIdx.x;   // exactly B*T threads
    int b = idx / 200;
    int t = idx - b * 200;
    const float4* kp  = (const float4*)(gru + ((size_t)b * 200 + t) * 64);
    const float4* qp  = (const float4*)(targets + (size_t)b * 64);
    const float4* qWv = (const float4*)(ws + 10240 + (size_t)b * 80);
    const float4* Wuq = (const float4*)Wu;   // uniform -> scalar loads
    const float4* Wrq = (const float4*)Wr;
    const float4* W2v = (const float4*)W2;   // [80][10 quads]
    const float4* b2v = (const float4*)b2;

    float4 h2[10];
#pragma unroll
    for (int j = 0; j < 10; j++) h2[j] = b2v[j];

    float xu, xr;

    // ---- pass 0: layer-1 cols 0..39 (+ gate x-dots) ----
    {
        float4 h1[10];
#pragma unroll
        for (int j = 0; j < 10; j++) h1[j] = qWv[j];
        float4 xum = {0.f, 0.f, 0.f, 0.f};
        float4 xrm = {0.f, 0.f, 0.f, 0.f};
#pragma unroll 4
        for (int i4 = 0; i4 < 16; i4++) {
            float4 kv = kp[i4];
            float4 qv = qp[i4];
            float4 wu = Wuq[i4];
            float4 wrv = Wrq[i4];
            xum.x = fmaf(kv.x, wu.x, xum.x); xum.y = fmaf(kv.y, wu.y, xum.y);
            xum.z = fmaf(kv.z, wu.z, xum.z); xum.w = fmaf(kv.w, wu.w, xum.w);
            xrm.x = fmaf(kv.x, wrv.x, xrm.x); xrm.y = fmaf(kv.y, wrv.y, xrm.y);
            xrm.z = fmaf(kv.z, wrv.z, xrm.z); xrm.w = fmaf(kv.w, wrv.w, xrm.w);
            float kk[4] = {kv.x, kv.y, kv.z, kv.w};
            float pp[4] = {qv.x * kv.x, qv.y * kv.y, qv.z * kv.z, qv.w * kv.w};
#pragma unroll
            for (int u = 0; u < 4; u++) {
                const float4* wk = &sWk[(i4 * 4 + u) * 20];
                const float4* wp = &sWp[(i4 * 4 + u) * 20];
                float ki = kk[u], pi = pp[u];
#pragma unroll
                for (int j = 0; j < 10; j++) {
                    float4 aa = wk[j], cc = wp[j];
                    h1[j].x = fmaf(ki, aa.x, fmaf(pi, cc.x, h1[j].x));
                    h1[j].y = fmaf(ki, aa.y, fmaf(pi, cc.y, h1[j].y));
                    h1[j].z = fmaf(ki, aa.z, fmaf(pi, cc.z, h1[j].z));
                    h1[j].w = fmaf(ki, aa.w, fmaf(pi, cc.w, h1[j].w));
                }
            }
        }
        xu = (xum.x + xum.y) + (xum.z + xum.w);
        xr = (xrm.x + xrm.y) + (xrm.z + xrm.w);
        // fold h1 (cols 0..39) into h2
#pragma unroll
        for (int iq = 0; iq < 10; iq++) {
            float4 hv = h1[iq];
            float hs[4] = {hv.x, hv.y, hv.z, hv.w};
#pragma unroll
            for (int u = 0; u < 4; u++) {
                float v = hs[u];
                const float4* wr2 = W2v + (iq * 4 + u) * 10;
#pragma unroll
                for (int j = 0; j < 10; j++) {
                    float4 w = wr2[j];
                    h2[j].x = fmaf(v, w.x, h2[j].x);
                    h2[j].y = fmaf(v, w.y, h2[j].y);
                    h2[j].z = fmaf(v, w.z, h2[j].z);
                    h2[j].w = fmaf(v, w.w, h2[j].w);
                }
            }
        }
    }
    if (xg) ((float2*)xg)[(size_t)t * BB + b] = make_float2(xu, xr);

    // ---- pass 1: layer-1 cols 40..79 ----
    {
        float4 h1[10];
#pragma unroll
        for (int j = 0; j < 10; j++) h1[j] = qWv[10 + j];
#pragma unroll 4
        for (int i4 = 0; i4 < 16; i4++) {
            float4 kv = kp[i4];
            float4 qv = qp[i4];
            float kk[4] = {kv.x, kv.y, kv.z, kv.w};
            float pp[4] = {qv.x * kv.x, qv.y * kv.y, qv.z * kv.z, qv.w * kv.w};
#pragma unroll
            for (int u = 0; u < 4; u++) {
                const float4* wk = &sWk[(i4 * 4 + u) * 20 + 10];
                const float4* wp = &sWp[(i4 * 4 + u) * 20 + 10];
                float ki = kk[u], pi = pp[u];
#pragma unroll
                for (int j = 0; j < 10; j++) {
                    float4 aa = wk[j], cc = wp[j];
                    h1[j].x = fmaf(ki, aa.x, fmaf(pi, cc.x, h1[j].x));
                    h1[j].y = fmaf(ki, aa.y, fmaf(pi, cc.y, h1[j].y));
                    h1[j].z = fmaf(ki, aa.z, fmaf(pi, cc.z, h1[j].z));
                    h1[j].w = fmaf(ki, aa.w, fmaf(pi, cc.w, h1[j].w));
                }
            }
        }
        // fold h1 (cols 40..79) into h2
#pragma unroll
        for (int iq = 0; iq < 10; iq++) {
            float4 hv = h1[iq];
            float hs[4] = {hv.x, hv.y, hv.z, hv.w};
#pragma unroll
            for (int u = 0; u < 4; u++) {
                float v = hs[u];
                const float4* wr2 = W2v + ((10 + iq) * 4 + u) * 10;
#pragma unroll
                for (int j = 0; j < 10; j++) {
                    float4 w = wr2[j];
                    h2[j].x = fmaf(v, w.x, h2[j].x);
                    h2[j].y = fmaf(v, w.y, h2[j].y);
                    h2[j].z = fmaf(v, w.z, h2[j].z);
                    h2[j].w = fmaf(v, w.w, h2[j].w);
                }
            }
        }
    }

    // final: 40 -> 1
    const float4* Wfv = (const float4*)Wf;
    float lg = bf[0];
#pragma unroll
    for (int j = 0; j < 10; j++) {
        float4 w = Wfv[j];
        lg = fmaf(h2[j].x, w.x, lg);
        lg = fmaf(h2[j].y, w.y, lg);
        lg = fmaf(h2[j].z, w.z, lg);
        lg = fmaf(h2[j].w, w.w, lg);
    }
    if (lg == 0.0f) lg = -INFINITY;
    logits[(size_t)t * BB + b] = lg;
}

// softmax over batch dim for each t; scores stored [T][B] (coalesced)
__global__ __launch_bounds__(256) void softmax_kernel(const float* __restrict__ logits,
                                                      float* __restrict__ scores) {
    int t = blockIdx.x;
    int tid = threadIdx.x;
    const float* L = logits + (size_t)t * BB;
    float v[16];
#pragma unroll
    for (int i = 0; i < 16; i++) {
        float x = L[tid + i * 256];
        v[i] = (x == 0.0f) ? -INFINITY : x;
    }
    float m = v[0];
#pragma unroll
    for (int i = 1; i < 16; i++) m = fmaxf(m, v[i]);
#pragma unroll
    for (int off = 32; off; off >>= 1) m = fmaxf(m, __shfl_xor(m, off));
    __shared__ float sm[4];
    __shared__ float ss[4];
    int wid = tid >> 6;
    if ((tid & 63) == 0) sm[wid] = m;
    __syncthreads();
    m = fmaxf(fmaxf(sm[0], sm[1]), fmaxf(sm[2], sm[3]));
    float e[16];
    float s = 0.0f;
#pragma unroll
    for (int i = 0; i < 16; i++) {
        e[i] = __expf(v[i] - m);
        s += e[i];
    }
#pragma unroll
    for (int off = 32; off; off >>= 1) s += __shfl_xor(s, off);
    if ((tid & 63) == 0) ss[wid] = s;
    __syncthreads();
    s = ss[0] + ss[1] + ss[2] + ss[3];
    float inv = 1.0f / s;
    float* S = scores + (size_t)t * BB;
#pragma unroll
    for (int i = 0; i < 16; i++) S[tid + i * 256] = e[i] * inv;
}

// Batched x-side precompute: xc[t][b][:] = gru[b][t][:] @ Wc[0:64][:] + bc.
__global__ __launch_bounds__(256) void xprep_kernel(
    const float* __restrict__ gru, const float* __restrict__ Wc,
    const float* __restrict__ bc, float* __restrict__ xc) {
    __shared__ float  Xs[32][65];
    __shared__ float4 Ws[1024];     // Wc1 quads: Ws[k*16+q] = Wc[k][4q..4q+3]
    const int tid = threadIdx.x;
    const int n0 = blockIdx.x * 32;
    const int nl = tid >> 3;        // 0..31 row in tile
    const int qs = tid & 7;         // 0..7 quad-pair selector

    const float4* Wq = (const float4*)Wc;   // first 64 rows contiguous
#pragma unroll
    for (int i = 0; i < 4; i++) Ws[tid * 4 + i] = Wq[tid * 4 + i];
    {
        const float4* gq = (const float4*)(gru + (size_t)(n0 + nl) * 64);
        float4 aa = gq[qs * 2];
        float4 bb = gq[qs * 2 + 1];
        float* xrow = &Xs[nl][qs * 8];
        xrow[0] = aa.x; xrow[1] = aa.y; xrow[2] = aa.z; xrow[3] = aa.w;
        xrow[4] = bb.x; xrow[5] = bb.y; xrow[6] = bb.z; xrow[7] = bb.w;
    }
    __syncthreads();

    const float4* bcq = (const float4*)bc;
    float4 acc0 = bcq[qs];
    float4 acc1 = bcq[qs + 8];
#pragma unroll
    for (int k = 0; k < 64; k++) {
        float  xk = Xs[nl][k];
        float4 w0 = Ws[k * 16 + qs];
        float4 w1 = Ws[k * 16 + qs + 8];
        acc0.x = fmaf(xk, w0.x, acc0.x);
        acc0.y = fmaf(xk, w0.y, acc0.y);
        acc0.z = fmaf(xk, w0.z, acc0.z);
        acc0.w = fmaf(xk, w0.w, acc0.w);
        acc1.x = fmaf(xk, w1.x, acc1.x);
        acc1.y = fmaf(xk, w1.y, acc1.y);
        acc1.z = fmaf(xk, w1.z, acc1.z);
        acc1.w = fmaf(xk, w1.w, acc1.w);
    }
    int n = n0 + nl;
    int b = n / 200;
    int t = n - b * 200;
    float4* o = (float4*)(xc + ((size_t)t * BB + b) * 64);
    o[qs]     = acc0;
    o[qs + 8] = acc1;
}

// Consumer-only AUGRU. 4 waves per block (4 b's, private LDS rows, zero
// barriers) to lift the 16-workgroup/CU cap; 2-deep prefetch of {xc,xg,sc}
// to cover HBM/L3 latency; DPP row_ror reduce (VALU) instead of 6-level
// shfl chains; 8 candidate accumulators to halve the fma chain depth.
__global__ __launch_bounds__(256, 4) void augru2_kernel(
    const float* __restrict__ xc, const float* __restrict__ xg,
    const float* __restrict__ scores,
    const float* __restrict__ Wu, const float* __restrict__ bu,
    const float* __restrict__ Wr, const float* __restrict__ br,
    const float* __restrict__ Wc, float* __restrict__ out) {
    __shared__ float hbuf[4][64];
    const int lane = threadIdx.x & 63;
    const int wid  = threadIdx.x >> 6;
    const int b    = blockIdx.x * 4 + wid;

    float wc2[64];
#pragma unroll
    for (int k = 0; k < 64; k++) wc2[k] = Wc[(64 + k) * 64 + lane];
    const float wu2l = Wu[64 + lane];
    const float wr2l = Wr[64 + lane];
    const float sbu = bu[0], sbr = br[0];
    const float2* xg2 = (const float2*)xg;

    float h = 0.0f;
    // 2-deep prefetch pipeline
    float  x0 = xc[(size_t)b * 64 + lane];
    float2 g0 = xg2[b];
    float  s0 = scores[b];
    size_t i1 = (size_t)BB + b;
    float  x1 = xc[i1 * 64 + lane];
    float2 g1 = xg2[i1];
    float  s1 = scores[i1];

    for (int t = 0; t < TT; t++) {
        float x2 = 0.0f, s2 = 0.0f;
        float2 g2 = make_float2(0.0f, 0.0f);
        if (t + 2 < TT) {
            size_t i2 = (size_t)(t + 2) * BB + b;
            x2 = xc[i2 * 64 + lane];
            g2 = xg2[i2];
            s2 = scores[i2];
        }

        hbuf[wid][lane] = h;   // same-wave LDS round-trip (DS pipe in-order)

        float pu = wave_sum64(h * wu2l);
        float pr = wave_sum64(h * wr2l);
        float u = s0 / (1.0f + __expf(-(pu + g0.x + sbu)));
        float r = 1.0f / (1.0f + __expf(-(pr + g0.y + sbr)));

        float a0 = 0.f, a1 = 0.f, a2 = 0.f, a3 = 0.f;
        float a4 = 0.f, a5 = 0.f, a6 = 0.f, a7 = 0.f;
        const float4* h4 = (const float4*)hbuf[wid];
#pragma unroll
        for (int kq = 0; kq < 8; kq++) {
            float4 hv0 = h4[2 * kq];
            float4 hv1 = h4[2 * kq + 1];
            a0 = fmaf(hv0.x, wc2[8 * kq + 0], a0);
            a1 = fmaf(hv0.y, wc2[8 * kq + 1], a1);
            a2 = fmaf(hv0.z, wc2[8 * kq + 2], a2);
            a3 = fmaf(hv0.w, wc2[8 * kq + 3], a3);
            a4 = fmaf(hv1.x, wc2[8 * kq + 4], a4);
            a5 = fmaf(hv1.y, wc2[8 * kq + 5], a5);
            a6 = fmaf(hv1.z, wc2[8 * kq + 6], a6);
            a7 = fmaf(hv1.w, wc2[8 * kq + 7], a7);
        }
        float cand = ((a0 + a1) + (a2 + a3)) + ((a4 + a5) + (a6 + a7));
        float arg = x0 + r * cand;
        float ex = __expf(2.0f * arg);   // tanh
        float th = 1.0f - 2.0f / (ex + 1.0f);
        h = fmaf(u, th - h, h);

        x0 = x1; g0 = g1; s0 = s1;
        x1 = x2; g1 = g2; s1 = s2;
    }
    out[(size_t)b * 64 + lane] = h;
}

// ---- fallback (small workspace): original fused producer/consumer AUGRU ----
__global__ __launch_bounds__(128, 4) void augru_kernel(
    const float* __restrict__ gru, const float* __restrict__ scores,
    const float* __restrict__ Wu, const float* __restrict__ bu,
    const float* __restrict__ Wr, const float* __restrict__ br,
    const float* __restrict__ Wc, const float* __restrict__ bc,
    float* __restrict__ out) {
    __shared__ float sxc[2][64];
    __shared__ float sxg[2][2];
    const int lane = threadIdx.x & 63;
    const int wid  = threadIdx.x >> 6;
    const int b    = blockIdx.x;
    const float* xrow = gru + (size_t)b * TT * 64;

    if (wid == 0) {
        float wc1[64];
#pragma unroll
        for (int k = 0; k < 64; k++) wc1[k] = Wc[k * 64 + lane];
        float wu1l = Wu[lane], wr1l = Wr[lane];
        float bcl = bc[lane];

        auto produce = [&](int tp, float xl) {
            float pu = xl * wu1l;
            float pr = xl * wr1l;
#pragma unroll
            for (int off = 32; off; off >>= 1) {
                pu += __shfl_xor(pu, off);
                pr += __shfl_xor(pr, off);
            }
            float a0 = bcl, a1 = 0.0f, a2 = 0.0f, a3 = 0.0f;
#pragma unroll
            for (int k = 0; k < 16; k++) {
                a0 = fmaf(lane_bcast(xl, 4 * k + 0), wc1[4 * k + 0], a0);
                a1 = fmaf(lane_bcast(xl, 4 * k + 1), wc1[4 * k + 1], a1);
                a2 = fmaf(lane_bcast(xl, 4 * k + 2), wc1[4 * k + 2], a2);
                a3 = fmaf(lane_bcast(xl, 4 * k + 3), wc1[4 * k + 3], a3);
            }
            int p = tp & 1;
            sxc[p][lane] = (a0 + a1) + (a2 + a3);
            if (lane == 0) sxg[p][0] = pu;
            if (lane == 1) sxg[p][1] = pr;
        };

        float xl = xrow[lane];
        float xn = xrow[64 + lane];
        produce(0, xl);
        xl = xn;
        __syncthreads();
        for (int t = 0; t < TT; t++) {
            if (t + 1 < TT) {
                float xnn = (t + 2 < TT) ? xrow[(size_t)(t + 2) * 64 + lane] : 0.0f;
                produce(t + 1, xl);
                xl = xnn;
            }
            __syncthreads();
        }
    } else {
        float wc2[64];
#pragma unroll
        for (int k = 0; k < 64; k++) wc2[k] = Wc[(64 + k) * 64 + lane];
        float wu2l = Wu[64 + lane], wr2l = Wr[64 + lane];
        float sbu = bu[0], sbr = br[0];
        float h = 0.0f;
        __syncthreads();
        for (int t = 0; t < TT; t++) {
            int p = t & 1;
            float sc = scores[(size_t)t * BB + b];
            float xcv = sxc[p][lane];
            float xu = sxg[p][0];
            float xv = sxg[p][1];
            float pu = h * wu2l;
            float pr = h * wr2l;
#pragma unroll
            for (int off = 32; off; off >>= 1) {
                pu += __shfl_xor(pu, off);
                pr += __shfl_xor(pr, off);
            }
            float u = sc / (1.0f + __expf(-(pu + xu + sbu)));
            float r = 1.0f / (1.0f + __expf(-(pr + xv + sbr)));
            float a0 = 0.0f, a1 = 0.0f, a2 = 0.0f, a3 = 0.0f;
#pragma unroll
            for (int k = 0; k < 16; k++) {
                a0 = fmaf(lane_bcast(h, 4 * k + 0), wc2[4 * k + 0], a0);
                a1 = fmaf(lane_bcast(h, 4 * k + 1), wc2[4 * k + 1], a1);
                a2 = fmaf(lane_bcast(h, 4 * k + 2), wc2[4 * k + 2], a2);
                a3 = fmaf(lane_bcast(h, 4 * k + 3), wc2[4 * k + 3], a3);
            }
            float arg = xcv + r * ((a0 + a1) + (a2 + a3));
            float ex = __expf(2.0f * arg);
            float th = 1.0f - 2.0f / (ex + 1.0f);
            h = fmaf(u, th - h, h);
            __syncthreads();
        }
        out[(size_t)b * 64 + lane] = h;
    }
}

extern "C" void kernel_launch(void* const* d_in, const int* in_sizes, int n_in,
                              void* d_out, int out_size, void* d_ws, size_t ws_size,
                              hipStream_t stream) {
    const float* gru     = (const float*)d_in[0];
    const float* targets = (const float*)d_in[1];
    const float* W1 = (const float*)d_in[2];
    const float* b1 = (const float*)d_in[3];
    const float* W2 = (const float*)d_in[4];
    const float* b2 = (const float*)d_in[5];
    const float* Wf = (const float*)d_in[6];
    const float* bf = (const float*)d_in[7];
    const float* Wu = (const float*)d_in[8];
    const float* bu = (const float*)d_in[9];
    const float* Wr = (const float*)d_in[10];
    const float* br = (const float*)d_in[11];
    const float* Wc = (const float*)d_in[12];
    const float* bc = (const float*)d_in[13];
    float* out = (float*)d_out;

    float* ws     = (float*)d_ws;
    float* logits = ws + 337920;
    float* scores = ws + 1157120;

    const bool big = (ws_size >= WS_NEED_BYTES);
    float* xg = big ? ws + OFF_XG : nullptr;
    float* xc = ws + OFF_XC;

    prep_kernel<<<20, 256, 0, stream>>>(W1, ws);
    qw_kernel<<<1280, 256, 0, stream>>>(targets, b1, ws, ws + 10240);
    mlp_kernel<<<3200, 256, 0, stream>>>(gru, targets, W1, W2, b2, Wf, bf, Wu, Wr,
                                         ws, logits, xg);
    softmax_kernel<<<200, 256, 0, stream>>>(logits, scores);
    if (big) {
        xprep_kernel<<<25600, 256, 0, stream>>>(gru, Wc, bc, xc);
        augru2_kernel<<<1024, 256, 0, stream>>>(xc, xg, scores, Wu, bu, Wr, br, Wc, out);
    } else {
        augru_kernel<<<4096, 128, 0, stream>>>(gru, scores, Wu, bu, Wr, br, Wc, bc, out);
    }
}

// Round 3
// 1228.013 us; speedup vs baseline: 1.4387x; 1.4387x over previous
//
#include <hip/hip_runtime.h>
#include <hip/hip_bf16.h>
#include <math.h>

#define BB 4096
#define TT 200
#define EE 64

// ws float layout:
//  [0,5120)          WkC = W1[64:128]-W1[128:192]   (64x80)
//  [5120,10240)      WqC = W1[0:64]+W1[128:192]     (64x80)
//  [10240,337920)    qW  = targets@WqC + b1         (B x 80)
//  [337920,1157120)  logits [T][B]
//  [1157120,1976320) scores [T][B]
//  -- big-ws path only --
//  [1976320,3614720) xg   [T][B] float2 {x.Wu1, x.Wr1}
//  [3614720,56043520) xc  [T][B][64] = x@Wc1 + bc
#define OFF_XG 1976320
#define OFF_XC 3614720
#define WS_NEED_BYTES ((size_t)(OFF_XC + (size_t)BB * TT * 64) * 4)

__device__ __forceinline__ float lane_bcast(float v, int l) {
    return __int_as_float(__builtin_amdgcn_readlane(__float_as_int(v), l));
}

// sum over all 64 lanes: 4 DPP row_ror adds (VALU, intra-row16) + 2 shfl levels
__device__ __forceinline__ float dpp_ror_add(float s, const int ctrl) {
    int t;
    switch (ctrl) {   // dpp_ctrl must be a literal constant
        case 8: t = __builtin_amdgcn_update_dpp(0, __float_as_int(s), 0x128, 0xF, 0xF, true); break;
        case 4: t = __builtin_amdgcn_update_dpp(0, __float_as_int(s), 0x124, 0xF, 0xF, true); break;
        case 2: t = __builtin_amdgcn_update_dpp(0, __float_as_int(s), 0x122, 0xF, 0xF, true); break;
        default: t = __builtin_amdgcn_update_dpp(0, __float_as_int(s), 0x121, 0xF, 0xF, true); break;
    }
    return s + __int_as_float(t);
}

__device__ __forceinline__ float wave_sum64(float v) {
    v = dpp_ror_add(v, 8);
    v = dpp_ror_add(v, 4);
    v = dpp_ror_add(v, 2);
    v = dpp_ror_add(v, 1);
    v += __shfl_xor(v, 16);
    v += __shfl_xor(v, 32);
    return v;
}

__global__ __launch_bounds__(256) void prep_kernel(const float* __restrict__ W1,
                                                   float* __restrict__ ws) {
    int idx = blockIdx.x * 256 + threadIdx.x;   // i*80+j, i<64
    if (idx >= 64 * 80) return;
    float wa = W1[idx];
    float wb = W1[64 * 80 + idx];
    float wc = W1[128 * 80 + idx];
    ws[idx]        = wb - wc;   // WkC
    ws[5120 + idx] = wa + wc;   // WqC
}

__global__ __launch_bounds__(256) void qw_kernel(const float* __restrict__ targets,
                                                 const float* __restrict__ b1,
                                                 const float* __restrict__ ws,
                                                 float* __restrict__ qW) {
    int idx = blockIdx.x * 256 + threadIdx.x;   // b*80+j
    int b = idx / 80;
    int j = idx - b * 80;
    const float* q  = targets + (size_t)b * 64;
    const float* Wq = ws + 5120;
    float s = b1[j];
#pragma unroll
    for (int i = 0; i < 64; i++) s = fmaf(q[i], Wq[i * 80 + j], s);
    qW[idx] = s;
}

// one thread per (b,t). Two-pass over the 80 layer-1 columns: live set is
// h2[10]f4 (persistent) + h1[10]f4 (per pass) + temps ~= 110 regs.
// launch_bounds(256,2): observed mapping on this toolchain is arg=4 -> 64-reg
// cap (round-2: VGPR=64, 1.19GB scratch writes, 1172us). arg=2 gives >=128,
// which fits the working set with zero spills.
__global__ __launch_bounds__(256, 2) void mlp_kernel(
    const float* __restrict__ gru, const float* __restrict__ targets,
    const float* __restrict__ W1, const float* __restrict__ W2,
    const float* __restrict__ b2, const float* __restrict__ Wf,
    const float* __restrict__ bf, const float* __restrict__ Wu,
    const float* __restrict__ Wr, const float* __restrict__ ws,
    float* __restrict__ logits, float* __restrict__ xg) {
    __shared__ float4 sWk[1280];   // [64][20 quads]
    __shared__ float4 sWp[1280];
    const float4* WkC = (const float4*)ws;              // 5120 floats
    const float4* Wp  = (const float4*)(W1 + 192 * 80); // last 64 rows of W1
    for (int i = threadIdx.x; i < 1280; i += 256) {
        sWk[i] = WkC[i];
        sWp[i] = Wp[i];
    }
    __syncthreads();

    int idx = blockIdx.x * 256 + threadIdx.x;   // exactly B*T threads
    int b = idx / 200;
    int t = idx - b * 200;
    const float4* kp  = (const float4*)(gru + ((size_t)b * 200 + t) * 64);
    const float4* qp  = (const float4*)(targets + (size_t)b * 64);
    const float4* qWv = (const float4*)(ws + 10240 + (size_t)b * 80);
    const float4* Wuq = (const float4*)Wu;   // uniform -> scalar loads
    const float4* Wrq = (const float4*)Wr;
    const float4* W2v = (const float4*)W2;   // [80][10 quads]
    const float4* b2v = (const float4*)b2;

    float4 h2[10];
#pragma unroll
    for (int j = 0; j < 10; j++) h2[j] = b2v[j];

    float xu, xr;

    // ---- pass 0: layer-1 cols 0..39 (+ gate x-dots) ----
    {
        float4 h1[10];
#pragma unroll
        for (int j = 0; j < 10; j++) h1[j] = qWv[j];
        float4 xum = {0.f, 0.f, 0.f, 0.f};
        float4 xrm = {0.f, 0.f, 0.f, 0.f};
#pragma unroll 2
        for (int i4 = 0; i4 < 16; i4++) {
            float4 kv = kp[i4];
            float4 qv = qp[i4];
            float4 wu = Wuq[i4];
            float4 wrv = Wrq[i4];
            xum.x = fmaf(kv.x, wu.x, xum.x); xum.y = fmaf(kv.y, wu.y, xum.y);
            xum.z = fmaf(kv.z, wu.z, xum.z); xum.w = fmaf(kv.w, wu.w, xum.w);
            xrm.x = fmaf(kv.x, wrv.x, xrm.x); xrm.y = fmaf(kv.y, wrv.y, xrm.y);
            xrm.z = fmaf(kv.z, wrv.z, xrm.z); xrm.w = fmaf(kv.w, wrv.w, xrm.w);
            float kk[4] = {kv.x, kv.y, kv.z, kv.w};
            float pp[4] = {qv.x * kv.x, qv.y * kv.y, qv.z * kv.z, qv.w * kv.w};
#pragma unroll
            for (int u = 0; u < 4; u++) {
                const float4* wk = &sWk[(i4 * 4 + u) * 20];
                const float4* wp = &sWp[(i4 * 4 + u) * 20];
                float ki = kk[u], pi = pp[u];
#pragma unroll
                for (int j = 0; j < 10; j++) {
                    float4 aa = wk[j], cc = wp[j];
                    h1[j].x = fmaf(ki, aa.x, fmaf(pi, cc.x, h1[j].x));
                    h1[j].y = fmaf(ki, aa.y, fmaf(pi, cc.y, h1[j].y));
                    h1[j].z = fmaf(ki, aa.z, fmaf(pi, cc.z, h1[j].z));
                    h1[j].w = fmaf(ki, aa.w, fmaf(pi, cc.w, h1[j].w));
                }
            }
        }
        xu = (xum.x + xum.y) + (xum.z + xum.w);
        xr = (xrm.x + xrm.y) + (xrm.z + xrm.w);
        // fold h1 (cols 0..39) into h2
#pragma unroll
        for (int iq = 0; iq < 10; iq++) {
            float4 hv = h1[iq];
            float hs[4] = {hv.x, hv.y, hv.z, hv.w};
#pragma unroll
            for (int u = 0; u < 4; u++) {
                float v = hs[u];
                const float4* wr2 = W2v + (iq * 4 + u) * 10;
#pragma unroll
                for (int j = 0; j < 10; j++) {
                    float4 w = wr2[j];
                    h2[j].x = fmaf(v, w.x, h2[j].x);
                    h2[j].y = fmaf(v, w.y, h2[j].y);
                    h2[j].z = fmaf(v, w.z, h2[j].z);
                    h2[j].w = fmaf(v, w.w, h2[j].w);
                }
            }
        }
    }
    if (xg) ((float2*)xg)[(size_t)t * BB + b] = make_float2(xu, xr);

    // ---- pass 1: layer-1 cols 40..79 ----
    {
        float4 h1[10];
#pragma unroll
        for (int j = 0; j < 10; j++) h1[j] = qWv[10 + j];
#pragma unroll 2
        for (int i4 = 0; i4 < 16; i4++) {
            float4 kv = kp[i4];
            float4 qv = qp[i4];
            float kk[4] = {kv.x, kv.y, kv.z, kv.w};
            float pp[4] = {qv.x * kv.x, qv.y * kv.y, qv.z * kv.z, qv.w * kv.w};
#pragma unroll
            for (int u = 0; u < 4; u++) {
                const float4* wk = &sWk[(i4 * 4 + u) * 20 + 10];
                const float4* wp = &sWp[(i4 * 4 + u) * 20 + 10];
                float ki = kk[u], pi = pp[u];
#pragma unroll
                for (int j = 0; j < 10; j++) {
                    float4 aa = wk[j], cc = wp[j];
                    h1[j].x = fmaf(ki, aa.x, fmaf(pi, cc.x, h1[j].x));
                    h1[j].y = fmaf(ki, aa.y, fmaf(pi, cc.y, h1[j].y));
                    h1[j].z = fmaf(ki, aa.z, fmaf(pi, cc.z, h1[j].z));
                    h1[j].w = fmaf(ki, aa.w, fmaf(pi, cc.w, h1[j].w));
                }
            }
        }
        // fold h1 (cols 40..79) into h2
#pragma unroll
        for (int iq = 0; iq < 10; iq++) {
            float4 hv = h1[iq];
            float hs[4] = {hv.x, hv.y, hv.z, hv.w};
#pragma unroll
            for (int u = 0; u < 4; u++) {
                float v = hs[u];
                const float4* wr2 = W2v + ((10 + iq) * 4 + u) * 10;
#pragma unroll
                for (int j = 0; j < 10; j++) {
                    float4 w = wr2[j];
                    h2[j].x = fmaf(v, w.x, h2[j].x);
                    h2[j].y = fmaf(v, w.y, h2[j].y);
                    h2[j].z = fmaf(v, w.z, h2[j].z);
                    h2[j].w = fmaf(v, w.w, h2[j].w);
                }
            }
        }
    }

    // final: 40 -> 1
    const float4* Wfv = (const float4*)Wf;
    float lg = bf[0];
#pragma unroll
    for (int j = 0; j < 10; j++) {
        float4 w = Wfv[j];
        lg = fmaf(h2[j].x, w.x, lg);
        lg = fmaf(h2[j].y, w.y, lg);
        lg = fmaf(h2[j].z, w.z, lg);
        lg = fmaf(h2[j].w, w.w, lg);
    }
    if (lg == 0.0f) lg = -INFINITY;
    logits[(size_t)t * BB + b] = lg;
}

// softmax over batch dim for each t; scores stored [T][B] (coalesced)
__global__ __launch_bounds__(256) void softmax_kernel(const float* __restrict__ logits,
                                                      float* __restrict__ scores) {
    int t = blockIdx.x;
    int tid = threadIdx.x;
    const float* L = logits + (size_t)t * BB;
    float v[16];
#pragma unroll
    for (int i = 0; i < 16; i++) {
        float x = L[tid + i * 256];
        v[i] = (x == 0.0f) ? -INFINITY : x;
    }
    float m = v[0];
#pragma unroll
    for (int i = 1; i < 16; i++) m = fmaxf(m, v[i]);
#pragma unroll
    for (int off = 32; off; off >>= 1) m = fmaxf(m, __shfl_xor(m, off));
    __shared__ float sm[4];
    __shared__ float ss[4];
    int wid = tid >> 6;
    if ((tid & 63) == 0) sm[wid] = m;
    __syncthreads();
    m = fmaxf(fmaxf(sm[0], sm[1]), fmaxf(sm[2], sm[3]));
    float e[16];
    float s = 0.0f;
#pragma unroll
    for (int i = 0; i < 16; i++) {
        e[i] = __expf(v[i] - m);
        s += e[i];
    }
#pragma unroll
    for (int off = 32; off; off >>= 1) s += __shfl_xor(s, off);
    if ((tid & 63) == 0) ss[wid] = s;
    __syncthreads();
    s = ss[0] + ss[1] + ss[2] + ss[3];
    float inv = 1.0f / s;
    float* S = scores + (size_t)t * BB;
#pragma unroll
    for (int i = 0; i < 16; i++) S[tid + i * 256] = e[i] * inv;
}

// Batched x-side precompute: xc[t][b][:] = gru[b][t][:] @ Wc[0:64][:] + bc.
__global__ __launch_bounds__(256) void xprep_kernel(
    const float* __restrict__ gru, const float* __restrict__ Wc,
    const float* __restrict__ bc, float* __restrict__ xc) {
    __shared__ float  Xs[32][65];
    __shared__ float4 Ws[1024];     // Wc1 quads: Ws[k*16+q] = Wc[k][4q..4q+3]
    const int tid = threadIdx.x;
    const int n0 = blockIdx.x * 32;
    const int nl = tid >> 3;        // 0..31 row in tile
    const int qs = tid & 7;         // 0..7 quad-pair selector

    const float4* Wq = (const float4*)Wc;   // first 64 rows contiguous
#pragma unroll
    for (int i = 0; i < 4; i++) Ws[tid * 4 + i] = Wq[tid * 4 + i];
    {
        const float4* gq = (const float4*)(gru + (size_t)(n0 + nl) * 64);
        float4 aa = gq[qs * 2];
        float4 bb = gq[qs * 2 + 1];
        float* xrow = &Xs[nl][qs * 8];
        xrow[0] = aa.x; xrow[1] = aa.y; xrow[2] = aa.z; xrow[3] = aa.w;
        xrow[4] = bb.x; xrow[5] = bb.y; xrow[6] = bb.z; xrow[7] = bb.w;
    }
    __syncthreads();

    const float4* bcq = (const float4*)bc;
    float4 acc0 = bcq[qs];
    float4 acc1 = bcq[qs + 8];
#pragma unroll
    for (int k = 0; k < 64; k++) {
        float  xk = Xs[nl][k];
        float4 w0 = Ws[k * 16 + qs];
        float4 w1 = Ws[k * 16 + qs + 8];
        acc0.x = fmaf(xk, w0.x, acc0.x);
        acc0.y = fmaf(xk, w0.y, acc0.y);
        acc0.z = fmaf(xk, w0.z, acc0.z);
        acc0.w = fmaf(xk, w0.w, acc0.w);
        acc1.x = fmaf(xk, w1.x, acc1.x);
        acc1.y = fmaf(xk, w1.y, acc1.y);
        acc1.z = fmaf(xk, w1.z, acc1.z);
        acc1.w = fmaf(xk, w1.w, acc1.w);
    }
    int n = n0 + nl;
    int b = n / 200;
    int t = n - b * 200;
    float4* o = (float4*)(xc + ((size_t)t * BB + b) * 64);
    o[qs]     = acc0;
    o[qs + 8] = acc1;
}

// Consumer-only AUGRU. 4 waves per block (4 b's, private LDS rows, zero
// barriers); 2-deep prefetch of {xc,xg,sc}; DPP row_ror reduce; 8 candidate
// accumulators. launch_bounds(256,2): wc2[64]+~35 temps ~= 100 live regs —
// needs a >=128 cap (arg=4 was observed to cap at 64).
__global__ __launch_bounds__(256, 2) void augru2_kernel(
    const float* __restrict__ xc, const float* __restrict__ xg,
    const float* __restrict__ scores,
    const float* __restrict__ Wu, const float* __restrict__ bu,
    const float* __restrict__ Wr, const float* __restrict__ br,
    const float* __restrict__ Wc, float* __restrict__ out) {
    __shared__ float hbuf[4][64];
    const int lane = threadIdx.x & 63;
    const int wid  = threadIdx.x >> 6;
    const int b    = blockIdx.x * 4 + wid;

    float wc2[64];
#pragma unroll
    for (int k = 0; k < 64; k++) wc2[k] = Wc[(64 + k) * 64 + lane];
    const float wu2l = Wu[64 + lane];
    const float wr2l = Wr[64 + lane];
    const float sbu = bu[0], sbr = br[0];
    const float2* xg2 = (const float2*)xg;

    float h = 0.0f;
    // 2-deep prefetch pipeline
    float  x0 = xc[(size_t)b * 64 + lane];
    float2 g0 = xg2[b];
    float  s0 = scores[b];
    size_t i1 = (size_t)BB + b;
    float  x1 = xc[i1 * 64 + lane];
    float2 g1 = xg2[i1];
    float  s1 = scores[i1];

    for (int t = 0; t < TT; t++) {
        float x2 = 0.0f, s2 = 0.0f;
        float2 g2 = make_float2(0.0f, 0.0f);
        if (t + 2 < TT) {
            size_t i2 = (size_t)(t + 2) * BB + b;
            x2 = xc[i2 * 64 + lane];
            g2 = xg2[i2];
            s2 = scores[i2];
        }

        hbuf[wid][lane] = h;   // same-wave LDS round-trip (DS pipe in-order)

        float pu = wave_sum64(h * wu2l);
        float pr = wave_sum64(h * wr2l);
        float u = s0 / (1.0f + __expf(-(pu + g0.x + sbu)));
        float r = 1.0f / (1.0f + __expf(-(pr + g0.y + sbr)));

        float a0 = 0.f, a1 = 0.f, a2 = 0.f, a3 = 0.f;
        float a4 = 0.f, a5 = 0.f, a6 = 0.f, a7 = 0.f;
        const float4* h4 = (const float4*)hbuf[wid];
#pragma unroll
        for (int kq = 0; kq < 8; kq++) {
            float4 hv0 = h4[2 * kq];
            float4 hv1 = h4[2 * kq + 1];
            a0 = fmaf(hv0.x, wc2[8 * kq + 0], a0);
            a1 = fmaf(hv0.y, wc2[8 * kq + 1], a1);
            a2 = fmaf(hv0.z, wc2[8 * kq + 2], a2);
            a3 = fmaf(hv0.w, wc2[8 * kq + 3], a3);
            a4 = fmaf(hv1.x, wc2[8 * kq + 4], a4);
            a5 = fmaf(hv1.y, wc2[8 * kq + 5], a5);
            a6 = fmaf(hv1.z, wc2[8 * kq + 6], a6);
            a7 = fmaf(hv1.w, wc2[8 * kq + 7], a7);
        }
        float cand = ((a0 + a1) + (a2 + a3)) + ((a4 + a5) + (a6 + a7));
        float arg = x0 + r * cand;
        float ex = __expf(2.0f * arg);   // tanh
        float th = 1.0f - 2.0f / (ex + 1.0f);
        h = fmaf(u, th - h, h);

        x0 = x1; g0 = g1; s0 = s1;
        x1 = x2; g1 = g2; s1 = s2;
    }
    out[(size_t)b * 64 + lane] = h;
}

// ---- fallback (small workspace): original fused producer/consumer AUGRU ----
__global__ __launch_bounds__(128, 4) void augru_kernel(
    const float* __restrict__ gru, const float* __restrict__ scores,
    const float* __restrict__ Wu, const float* __restrict__ bu,
    const float* __restrict__ Wr, const float* __restrict__ br,
    const float* __restrict__ Wc, const float* __restrict__ bc,
    float* __restrict__ out) {
    __shared__ float sxc[2][64];
    __shared__ float sxg[2][2];
    const int lane = threadIdx.x & 63;
    const int wid  = threadIdx.x >> 6;
    const int b    = blockIdx.x;
    const float* xrow = gru + (size_t)b * TT * 64;

    if (wid == 0) {
        float wc1[64];
#pragma unroll
        for (int k = 0; k < 64; k++) wc1[k] = Wc[k * 64 + lane];
        float wu1l = Wu[lane], wr1l = Wr[lane];
        float bcl = bc[lane];

        auto produce = [&](int tp, float xl) {
            float pu = xl * wu1l;
            float pr = xl * wr1l;
#pragma unroll
            for (int off = 32; off; off >>= 1) {
                pu += __shfl_xor(pu, off);
                pr += __shfl_xor(pr, off);
            }
            float a0 = bcl, a1 = 0.0f, a2 = 0.0f, a3 = 0.0f;
#pragma unroll
            for (int k = 0; k < 16; k++) {
                a0 = fmaf(lane_bcast(xl, 4 * k + 0), wc1[4 * k + 0], a0);
                a1 = fmaf(lane_bcast(xl, 4 * k + 1), wc1[4 * k + 1], a1);
                a2 = fmaf(lane_bcast(xl, 4 * k + 2), wc1[4 * k + 2], a2);
                a3 = fmaf(lane_bcast(xl, 4 * k + 3), wc1[4 * k + 3], a3);
            }
            int p = tp & 1;
            sxc[p][lane] = (a0 + a1) + (a2 + a3);
            if (lane == 0) sxg[p][0] = pu;
            if (lane == 1) sxg[p][1] = pr;
        };

        float xl = xrow[lane];
        float xn = xrow[64 + lane];
        produce(0, xl);
        xl = xn;
        __syncthreads();
        for (int t = 0; t < TT; t++) {
            if (t + 1 < TT) {
                float xnn = (t + 2 < TT) ? xrow[(size_t)(t + 2) * 64 + lane] : 0.0f;
                produce(t + 1, xl);
                xl = xnn;
            }
            __syncthreads();
        }
    } else {
        float wc2[64];
#pragma unroll
        for (int k = 0; k < 64; k++) wc2[k] = Wc[(64 + k) * 64 + lane];
        float wu2l = Wu[64 + lane], wr2l = Wr[64 + lane];
        float sbu = bu[0], sbr = br[0];
        float h = 0.0f;
        __syncthreads();
        for (int t = 0; t < TT; t++) {
            int p = t & 1;
            float sc = scores[(size_t)t * BB + b];
            float xcv = sxc[p][lane];
            float xu = sxg[p][0];
            float xv = sxg[p][1];
            float pu = h * wu2l;
            float pr = h * wr2l;
#pragma unroll
            for (int off = 32; off; off >>= 1) {
                pu += __shfl_xor(pu, off);
                pr += __shfl_xor(pr, off);
            }
            float u = sc / (1.0f + __expf(-(pu + xu + sbu)));
            float r = 1.0f / (1.0f + __expf(-(pr + xv + sbr)));
            float a0 = 0.0f, a1 = 0.0f, a2 = 0.0f, a3 = 0.0f;
#pragma unroll
            for (int k = 0; k < 16; k++) {
                a0 = fmaf(lane_bcast(h, 4 * k + 0), wc2[4 * k + 0], a0);
                a1 = fmaf(lane_bcast(h, 4 * k + 1), wc2[4 * k + 1], a1);
                a2 = fmaf(lane_bcast(h, 4 * k + 2), wc2[4 * k + 2], a2);
                a3 = fmaf(lane_bcast(h, 4 * k + 3), wc2[4 * k + 3], a3);
            }
            float arg = xcv + r * ((a0 + a1) + (a2 + a3));
            float ex = __expf(2.0f * arg);
            float th = 1.0f - 2.0f / (ex + 1.0f);
            h = fmaf(u, th - h, h);
            __syncthreads();
        }
        out[(size_t)b * 64 + lane] = h;
    }
}

extern "C" void kernel_launch(void* const* d_in, const int* in_sizes, int n_in,
                              void* d_out, int out_size, void* d_ws, size_t ws_size,
                              hipStream_t stream) {
    const float* gru     = (const float*)d_in[0];
    const float* targets = (const float*)d_in[1];
    const float* W1 = (const float*)d_in[2];
    const float* b1 = (const float*)d_in[3];
    const float* W2 = (const float*)d_in[4];
    const float* b2 = (const float*)d_in[5];
    const float* Wf = (const float*)d_in[6];
    const float* bf = (const float*)d_in[7];
    const float* Wu = (const float*)d_in[8];
    const float* bu = (const float*)d_in[9];
    const float* Wr = (const float*)d_in[10];
    const float* br = (const float*)d_in[11];
    const float* Wc = (const float*)d_in[12];
    const float* bc = (const float*)d_in[13];
    float* out = (float*)d_out;

    float* ws     = (float*)d_ws;
    float* logits = ws + 337920;
    float* scores = ws + 1157120;

    const bool big = (ws_size >= WS_NEED_BYTES);
    float* xg = big ? ws + OFF_XG : nullptr;
    float* xc = ws + OFF_XC;

    prep_kernel<<<20, 256, 0, stream>>>(W1, ws);
    qw_kernel<<<1280, 256, 0, stream>>>(targets, b1, ws, ws + 10240);
    mlp_kernel<<<3200, 256, 0, stream>>>(gru, targets, W1, W2, b2, Wf, bf, Wu, Wr,
                                         ws, logits, xg);
    softmax_kernel<<<200, 256, 0, stream>>>(logits, scores);
    if (big) {
        xprep_kernel<<<25600, 256, 0, stream>>>(gru, Wc, bc, xc);
        augru2_kernel<<<1024, 256, 0, stream>>>(xc, xg, scores, Wu, bu, Wr, br, Wc, out);
    } else {
        augru_kernel<<<4096, 128, 0, stream>>>(gru, scores, Wu, bu, Wr, br, Wc, bc, out);
    }
}

// Round 4
// 844.307 us; speedup vs baseline: 2.0925x; 1.4545x over previous
//
#include <hip/hip_runtime.h>
#include <hip/hip_bf16.h>
#include <math.h>

#define BB 4096
#define TT 200
#define EE 64

// ws float layout:
//  [0,64)     A = e_k - e_d      (coeff of k)
//  [64,128)   P = e_p            (coeff of q*k)
//  [128,192)  Q = e_q + e_d      (coeff of q)
//  [192]      c0 (scalar offset)
//  [337920,1157120)  logits [T][B]
//  [1157120,1976320) scores [T][B]
//  -- big-ws path only --
//  [1976320,3614720)  xg [T][B] float2 {x.Wu1, x.Wr1}
//  [3614720,56043520) xc [T][B][64] = x@Wc1 + bc
#define OFF_XG 1976320
#define OFF_XC 3614720
#define WS_NEED_BYTES ((size_t)(OFF_XC + (size_t)BB * TT * 64) * 4)

__device__ __forceinline__ float lane_bcast(float v, int l) {
    return __int_as_float(__builtin_amdgcn_readlane(__float_as_int(v), l));
}

// sum over all 64 lanes: 4 DPP row_ror adds (VALU, intra-row16) + 2 shfl levels
__device__ __forceinline__ float dpp_ror_add(float s, const int ctrl) {
    int t;
    switch (ctrl) {   // dpp_ctrl must be a literal constant
        case 8: t = __builtin_amdgcn_update_dpp(0, __float_as_int(s), 0x128, 0xF, 0xF, true); break;
        case 4: t = __builtin_amdgcn_update_dpp(0, __float_as_int(s), 0x124, 0xF, 0xF, true); break;
        case 2: t = __builtin_amdgcn_update_dpp(0, __float_as_int(s), 0x122, 0xF, 0xF, true); break;
        default: t = __builtin_amdgcn_update_dpp(0, __float_as_int(s), 0x121, 0xF, 0xF, true); break;
    }
    return s + __int_as_float(t);
}

__device__ __forceinline__ float wave_sum64(float v) {
    v = dpp_ror_add(v, 8);
    v = dpp_ror_add(v, 4);
    v = dpp_ror_add(v, 2);
    v = dpp_ror_add(v, 1);
    v += __shfl_xor(v, 16);
    v += __shfl_xor(v, 32);
    return v;
}

// The attention MLP (256->80->40->1) has NO activations => fully linear.
// logit(b,t) = sum_i [ q_i*(e_q+e_d)_i + k_i*(e_k-e_d)_i + q_i*k_i*e_p_i ] + c0
// with e = W1 @ (W2 @ Wf). This kernel computes the e-vectors and c0 once.
__global__ __launch_bounds__(128) void weff_kernel(
    const float* __restrict__ W1, const float* __restrict__ b1,
    const float* __restrict__ W2, const float* __restrict__ b2,
    const float* __restrict__ Wf, const float* __restrict__ bf,
    float* __restrict__ ws) {
    __shared__ float t80[80];
    int tid = threadIdx.x;
    if (tid < 80) {
        float s = 0.0f;
        for (int j = 0; j < 40; j++) s = fmaf(W2[tid * 40 + j], Wf[j], s);
        t80[tid] = s;
    }
    __syncthreads();
    if (tid < 64) {
        float eq = 0.f, ek = 0.f, ed = 0.f, ep = 0.f;
        for (int m = 0; m < 80; m++) {
            float t = t80[m];
            eq = fmaf(W1[tid * 80 + m],         t, eq);
            ek = fmaf(W1[(64 + tid) * 80 + m],  t, ek);
            ed = fmaf(W1[(128 + tid) * 80 + m], t, ed);
            ep = fmaf(W1[(192 + tid) * 80 + m], t, ep);
        }
        ws[tid]       = ek - ed;   // A
        ws[64 + tid]  = ep;        // P
        ws[128 + tid] = eq + ed;   // Q
    } else if (tid == 64) {
        float s = bf[0];
        for (int m = 0; m < 80; m++) s = fmaf(b1[m], t80[m], s);
        for (int j = 0; j < 40; j++) s = fmaf(b2[j], Wf[j], s);
        ws[192] = s;               // c0
    }
}

// logit per (b,t): 64-wide fused dot, 3 fma/element, ~12 live regs.
// HBM-bound on the single gru read (210 MB).
__global__ __launch_bounds__(256) void logits_kernel(
    const float* __restrict__ gru, const float* __restrict__ targets,
    const float* __restrict__ ws, float* __restrict__ logits) {
    __shared__ float4 sA[16], sP[16], sQ[16];
    __shared__ float sc0;
    int tid = threadIdx.x;
    if (tid < 16) {
        sA[tid] = ((const float4*)ws)[tid];
        sP[tid] = ((const float4*)(ws + 64))[tid];
        sQ[tid] = ((const float4*)(ws + 128))[tid];
    }
    if (tid == 16) sc0 = ws[192];
    __syncthreads();

    int idx = blockIdx.x * 256 + tid;   // exactly B*T threads
    int b = idx / 200;
    int t = idx - b * 200;
    const float4* kp = (const float4*)(gru + ((size_t)b * 200 + t) * 64);
    const float4* qp = (const float4*)(targets + (size_t)b * 64);

    float a0 = sc0, a1 = 0.f, a2 = 0.f, a3 = 0.f;
#pragma unroll
    for (int i = 0; i < 16; i++) {
        float4 kv = kp[i], qv = qp[i], A = sA[i], P = sP[i], Q = sQ[i];
        a0 = fmaf(qv.x, Q.x, a0); a0 = fmaf(kv.x, fmaf(qv.x, P.x, A.x), a0);
        a1 = fmaf(qv.y, Q.y, a1); a1 = fmaf(kv.y, fmaf(qv.y, P.y, A.y), a1);
        a2 = fmaf(qv.z, Q.z, a2); a2 = fmaf(kv.z, fmaf(qv.z, P.z, A.z), a2);
        a3 = fmaf(qv.w, Q.w, a3); a3 = fmaf(kv.w, fmaf(qv.w, P.w, A.w), a3);
    }
    float lg = (a0 + a1) + (a2 + a3);
    if (lg == 0.0f) lg = -INFINITY;
    logits[(size_t)t * BB + b] = lg;
}

// softmax over batch dim for each t; scores stored [T][B] (coalesced)
__global__ __launch_bounds__(256) void softmax_kernel(const float* __restrict__ logits,
                                                      float* __restrict__ scores) {
    int t = blockIdx.x;
    int tid = threadIdx.x;
    const float* L = logits + (size_t)t * BB;
    float v[16];
#pragma unroll
    for (int i = 0; i < 16; i++) {
        float x = L[tid + i * 256];
        v[i] = (x == 0.0f) ? -INFINITY : x;
    }
    float m = v[0];
#pragma unroll
    for (int i = 1; i < 16; i++) m = fmaxf(m, v[i]);
#pragma unroll
    for (int off = 32; off; off >>= 1) m = fmaxf(m, __shfl_xor(m, off));
    __shared__ float sm[4];
    __shared__ float ss[4];
    int wid = tid >> 6;
    if ((tid & 63) == 0) sm[wid] = m;
    __syncthreads();
    m = fmaxf(fmaxf(sm[0], sm[1]), fmaxf(sm[2], sm[3]));
    float e[16];
    float s = 0.0f;
#pragma unroll
    for (int i = 0; i < 16; i++) {
        e[i] = __expf(v[i] - m);
        s += e[i];
    }
#pragma unroll
    for (int off = 32; off; off >>= 1) s += __shfl_xor(s, off);
    if ((tid & 63) == 0) ss[wid] = s;
    __syncthreads();
    s = ss[0] + ss[1] + ss[2] + ss[3];
    float inv = 1.0f / s;
    float* S = scores + (size_t)t * BB;
#pragma unroll
    for (int i = 0; i < 16; i++) S[tid + i * 256] = e[i] * inv;
}

// Batched x-side precompute: xc[t][b][:] = gru[b][t][:] @ Wc[0:64][:] + bc,
// plus the AUGRU gate x-dots xg[t][b] = {x.Wu1, x.Wr1} (the row is already
// staged in LDS here, so the gate dots are nearly free).
__global__ __launch_bounds__(256) void xprep_kernel(
    const float* __restrict__ gru, const float* __restrict__ Wc,
    const float* __restrict__ bc, const float* __restrict__ Wu,
    const float* __restrict__ Wr, float* __restrict__ xc,
    float* __restrict__ xg) {
    __shared__ float  Xs[32][65];
    __shared__ float4 Ws[1024];     // Wc1 quads: Ws[k*16+q] = Wc[k][4q..4q+3]
    __shared__ float  Wg[128];      // Wu[0:64] | Wr[0:64]
    const int tid = threadIdx.x;
    const int n0 = blockIdx.x * 32;
    const int nl = tid >> 3;        // 0..31 row in tile
    const int qs = tid & 7;         // 0..7 quad-pair selector

    const float4* Wq = (const float4*)Wc;   // first 64 rows contiguous
#pragma unroll
    for (int i = 0; i < 4; i++) Ws[tid * 4 + i] = Wq[tid * 4 + i];
    if (tid < 128) Wg[tid] = (tid < 64) ? Wu[tid] : Wr[tid - 64];
    {
        const float4* gq = (const float4*)(gru + (size_t)(n0 + nl) * 64);
        float4 aa = gq[qs * 2];
        float4 bb = gq[qs * 2 + 1];
        float* xrow = &Xs[nl][qs * 8];
        xrow[0] = aa.x; xrow[1] = aa.y; xrow[2] = aa.z; xrow[3] = aa.w;
        xrow[4] = bb.x; xrow[5] = bb.y; xrow[6] = bb.z; xrow[7] = bb.w;
    }
    __syncthreads();

    const float4* bcq = (const float4*)bc;
    float4 acc0 = bcq[qs];
    float4 acc1 = bcq[qs + 8];
#pragma unroll
    for (int k = 0; k < 64; k++) {
        float  xk = Xs[nl][k];
        float4 w0 = Ws[k * 16 + qs];
        float4 w1 = Ws[k * 16 + qs + 8];
        acc0.x = fmaf(xk, w0.x, acc0.x);
        acc0.y = fmaf(xk, w0.y, acc0.y);
        acc0.z = fmaf(xk, w0.z, acc0.z);
        acc0.w = fmaf(xk, w0.w, acc0.w);
        acc1.x = fmaf(xk, w1.x, acc1.x);
        acc1.y = fmaf(xk, w1.y, acc1.y);
        acc1.z = fmaf(xk, w1.z, acc1.z);
        acc1.w = fmaf(xk, w1.w, acc1.w);
    }
    int n = n0 + nl;
    int b = n / 200;
    int t = n - b * 200;
    float4* o = (float4*)(xc + ((size_t)t * BB + b) * 64);
    o[qs]     = acc0;
    o[qs + 8] = acc1;
    if (qs == 0) {
        float su = 0.f, sr = 0.f;
#pragma unroll
        for (int k = 0; k < 64; k++) {
            float xk = Xs[nl][k];
            su = fmaf(xk, Wg[k], su);
            sr = fmaf(xk, Wg[64 + k], sr);
        }
        ((float2*)xg)[(size_t)t * BB + b] = make_float2(su, sr);
    }
}

// Consumer-only AUGRU. 4 waves per block (4 b's, private LDS rows, zero
// barriers); 2-deep prefetch of {xc,xg,sc}; DPP row_ror reduce; 8 candidate
// accumulators.
__global__ __launch_bounds__(256, 2) void augru2_kernel(
    const float* __restrict__ xc, const float* __restrict__ xg,
    const float* __restrict__ scores,
    const float* __restrict__ Wu, const float* __restrict__ bu,
    const float* __restrict__ Wr, const float* __restrict__ br,
    const float* __restrict__ Wc, float* __restrict__ out) {
    __shared__ float hbuf[4][64];
    const int lane = threadIdx.x & 63;
    const int wid  = threadIdx.x >> 6;
    const int b    = blockIdx.x * 4 + wid;

    float wc2[64];
#pragma unroll
    for (int k = 0; k < 64; k++) wc2[k] = Wc[(64 + k) * 64 + lane];
    const float wu2l = Wu[64 + lane];
    const float wr2l = Wr[64 + lane];
    const float sbu = bu[0], sbr = br[0];
    const float2* xg2 = (const float2*)xg;

    float h = 0.0f;
    // 2-deep prefetch pipeline
    float  x0 = xc[(size_t)b * 64 + lane];
    float2 g0 = xg2[b];
    float  s0 = scores[b];
    size_t i1 = (size_t)BB + b;
    float  x1 = xc[i1 * 64 + lane];
    float2 g1 = xg2[i1];
    float  s1 = scores[i1];

    for (int t = 0; t < TT; t++) {
        float x2 = 0.0f, s2 = 0.0f;
        float2 g2 = make_float2(0.0f, 0.0f);
        if (t + 2 < TT) {
            size_t i2 = (size_t)(t + 2) * BB + b;
            x2 = xc[i2 * 64 + lane];
            g2 = xg2[i2];
            s2 = scores[i2];
        }

        hbuf[wid][lane] = h;   // same-wave LDS round-trip (DS pipe in-order)

        float pu = wave_sum64(h * wu2l);
        float pr = wave_sum64(h * wr2l);
        float u = s0 / (1.0f + __expf(-(pu + g0.x + sbu)));
        float r = 1.0f / (1.0f + __expf(-(pr + g0.y + sbr)));

        float a0 = 0.f, a1 = 0.f, a2 = 0.f, a3 = 0.f;
        float a4 = 0.f, a5 = 0.f, a6 = 0.f, a7 = 0.f;
        const float4* h4 = (const float4*)hbuf[wid];
#pragma unroll
        for (int kq = 0; kq < 8; kq++) {
            float4 hv0 = h4[2 * kq];
            float4 hv1 = h4[2 * kq + 1];
            a0 = fmaf(hv0.x, wc2[8 * kq + 0], a0);
            a1 = fmaf(hv0.y, wc2[8 * kq + 1], a1);
            a2 = fmaf(hv0.z, wc2[8 * kq + 2], a2);
            a3 = fmaf(hv0.w, wc2[8 * kq + 3], a3);
            a4 = fmaf(hv1.x, wc2[8 * kq + 4], a4);
            a5 = fmaf(hv1.y, wc2[8 * kq + 5], a5);
            a6 = fmaf(hv1.z, wc2[8 * kq + 6], a6);
            a7 = fmaf(hv1.w, wc2[8 * kq + 7], a7);
        }
        float cand = ((a0 + a1) + (a2 + a3)) + ((a4 + a5) + (a6 + a7));
        float arg = x0 + r * cand;
        float ex = __expf(2.0f * arg);   // tanh
        float th = 1.0f - 2.0f / (ex + 1.0f);
        h = fmaf(u, th - h, h);

        x0 = x1; g0 = g1; s0 = s1;
        x1 = x2; g1 = g2; s1 = s2;
    }
    out[(size_t)b * 64 + lane] = h;
}

// ---- fallback (small workspace): original fused producer/consumer AUGRU ----
__global__ __launch_bounds__(128, 4) void augru_kernel(
    const float* __restrict__ gru, const float* __restrict__ scores,
    const float* __restrict__ Wu, const float* __restrict__ bu,
    const float* __restrict__ Wr, const float* __restrict__ br,
    const float* __restrict__ Wc, const float* __restrict__ bc,
    float* __restrict__ out) {
    __shared__ float sxc[2][64];
    __shared__ float sxg[2][2];
    const int lane = threadIdx.x & 63;
    const int wid  = threadIdx.x >> 6;
    const int b    = blockIdx.x;
    const float* xrow = gru + (size_t)b * TT * 64;

    if (wid == 0) {
        float wc1[64];
#pragma unroll
        for (int k = 0; k < 64; k++) wc1[k] = Wc[k * 64 + lane];
        float wu1l = Wu[lane], wr1l = Wr[lane];
        float bcl = bc[lane];

        auto produce = [&](int tp, float xl) {
            float pu = xl * wu1l;
            float pr = xl * wr1l;
#pragma unroll
            for (int off = 32; off; off >>= 1) {
                pu += __shfl_xor(pu, off);
                pr += __shfl_xor(pr, off);
            }
            float a0 = bcl, a1 = 0.0f, a2 = 0.0f, a3 = 0.0f;
#pragma unroll
            for (int k = 0; k < 16; k++) {
                a0 = fmaf(lane_bcast(xl, 4 * k + 0), wc1[4 * k + 0], a0);
                a1 = fmaf(lane_bcast(xl, 4 * k + 1), wc1[4 * k + 1], a1);
                a2 = fmaf(lane_bcast(xl, 4 * k + 2), wc1[4 * k + 2], a2);
                a3 = fmaf(lane_bcast(xl, 4 * k + 3), wc1[4 * k + 3], a3);
            }
            int p = tp & 1;
            sxc[p][lane] = (a0 + a1) + (a2 + a3);
            if (lane == 0) sxg[p][0] = pu;
            if (lane == 1) sxg[p][1] = pr;
        };

        float xl = xrow[lane];
        float xn = xrow[64 + lane];
        produce(0, xl);
        xl = xn;
        __syncthreads();
        for (int t = 0; t < TT; t++) {
            if (t + 1 < TT) {
                float xnn = (t + 2 < TT) ? xrow[(size_t)(t + 2) * 64 + lane] : 0.0f;
                produce(t + 1, xl);
                xl = xnn;
            }
            __syncthreads();
        }
    } else {
        float wc2[64];
#pragma unroll
        for (int k = 0; k < 64; k++) wc2[k] = Wc[(64 + k) * 64 + lane];
        float wu2l = Wu[64 + lane], wr2l = Wr[64 + lane];
        float sbu = bu[0], sbr = br[0];
        float h = 0.0f;
        __syncthreads();
        for (int t = 0; t < TT; t++) {
            int p = t & 1;
            float sc = scores[(size_t)t * BB + b];
            float xcv = sxc[p][lane];
            float xu = sxg[p][0];
            float xv = sxg[p][1];
            float pu = h * wu2l;
            float pr = h * wr2l;
#pragma unroll
            for (int off = 32; off; off >>= 1) {
                pu += __shfl_xor(pu, off);
                pr += __shfl_xor(pr, off);
            }
            float u = sc / (1.0f + __expf(-(pu + xu + sbu)));
            float r = 1.0f / (1.0f + __expf(-(pr + xv + sbr)));
            float a0 = 0.0f, a1 = 0.0f, a2 = 0.0f, a3 = 0.0f;
#pragma unroll
            for (int k = 0; k < 16; k++) {
                a0 = fmaf(lane_bcast(h, 4 * k + 0), wc2[4 * k + 0], a0);
                a1 = fmaf(lane_bcast(h, 4 * k + 1), wc2[4 * k + 1], a1);
                a2 = fmaf(lane_bcast(h, 4 * k + 2), wc2[4 * k + 2], a2);
                a3 = fmaf(lane_bcast(h, 4 * k + 3), wc2[4 * k + 3], a3);
            }
            float arg = xcv + r * ((a0 + a1) + (a2 + a3));
            float ex = __expf(2.0f * arg);
            float th = 1.0f - 2.0f / (ex + 1.0f);
            h = fmaf(u, th - h, h);
            __syncthreads();
        }
        out[(size_t)b * 64 + lane] = h;
    }
}

extern "C" void kernel_launch(void* const* d_in, const int* in_sizes, int n_in,
                              void* d_out, int out_size, void* d_ws, size_t ws_size,
                              hipStream_t stream) {
    const float* gru     = (const float*)d_in[0];
    const float* targets = (const float*)d_in[1];
    const float* W1 = (const float*)d_in[2];
    const float* b1 = (const float*)d_in[3];
    const float* W2 = (const float*)d_in[4];
    const float* b2 = (const float*)d_in[5];
    const float* Wf = (const float*)d_in[6];
    const float* bf = (const float*)d_in[7];
    const float* Wu = (const float*)d_in[8];
    const float* bu = (const float*)d_in[9];
    const float* Wr = (const float*)d_in[10];
    const float* br = (const float*)d_in[11];
    const float* Wc = (const float*)d_in[12];
    const float* bc = (const float*)d_in[13];
    float* out = (float*)d_out;

    float* ws     = (float*)d_ws;
    float* logits = ws + 337920;
    float* scores = ws + 1157120;

    const bool big = (ws_size >= WS_NEED_BYTES);
    float* xg = ws + OFF_XG;
    float* xc = ws + OFF_XC;

    weff_kernel<<<1, 128, 0, stream>>>(W1, b1, W2, b2, Wf, bf, ws);
    logits_kernel<<<3200, 256, 0, stream>>>(gru, targets, ws, logits);
    softmax_kernel<<<200, 256, 0, stream>>>(logits, scores);
    if (big) {
        xprep_kernel<<<25600, 256, 0, stream>>>(gru, Wc, bc, Wu, Wr, xc, xg);
        augru2_kernel<<<1024, 256, 0, stream>>>(xc, xg, scores, Wu, bu, Wr, br, Wc, out);
    } else {
        augru_kernel<<<4096, 128, 0, stream>>>(gru, scores, Wu, bu, Wr, br, Wc, bc, out);
    }
}

// Round 5
// 690.990 us; speedup vs baseline: 2.5568x; 1.2219x over previous
//
#include <hip/hip_runtime.h>
#include <hip/hip_bf16.h>
#include <math.h>

#define BB 4096
#define TT 200
#define EE 64

typedef float v2f __attribute__((ext_vector_type(2)));

// ws float layout:
//  [0,64)     A = e_k - e_d      (coeff of k)
//  [64,128)   P = e_p            (coeff of q*k)
//  [128,192)  Q = e_q + e_d      (coeff of q)
//  [192]      c0 (scalar offset)
//  [337920,1157120)  logits [T][B]
//  [1157120,1976320) scores [T][B]
//  -- big-ws path only --
//  [1976320,3614720)  xg [B][T] float2 {x.Wu1, x.Wr1}   (index = n = b*200+t)
//  [3614720,56043520) xc [B][T][64] = x@Wc1 + bc        (row n contiguous)
#define OFF_XG 1976320
#define OFF_XC 3614720
#define WS_NEED_BYTES ((size_t)(OFF_XC + (size_t)BB * TT * 64) * 4)

__device__ __forceinline__ float lane_bcast(float v, int l) {
    return __int_as_float(__builtin_amdgcn_readlane(__float_as_int(v), l));
}

// sum over all 64 lanes: 4 DPP row_ror adds (VALU, intra-row16) + 2 shfl levels
__device__ __forceinline__ float dpp_ror_add(float s, const int ctrl) {
    int t;
    switch (ctrl) {   // dpp_ctrl must be a literal constant
        case 8: t = __builtin_amdgcn_update_dpp(0, __float_as_int(s), 0x128, 0xF, 0xF, true); break;
        case 4: t = __builtin_amdgcn_update_dpp(0, __float_as_int(s), 0x124, 0xF, 0xF, true); break;
        case 2: t = __builtin_amdgcn_update_dpp(0, __float_as_int(s), 0x122, 0xF, 0xF, true); break;
        default: t = __builtin_amdgcn_update_dpp(0, __float_as_int(s), 0x121, 0xF, 0xF, true); break;
    }
    return s + __int_as_float(t);
}

__device__ __forceinline__ float wave_sum64(float v) {
    v = dpp_ror_add(v, 8);
    v = dpp_ror_add(v, 4);
    v = dpp_ror_add(v, 2);
    v = dpp_ror_add(v, 1);
    v += __shfl_xor(v, 16);
    v += __shfl_xor(v, 32);
    return v;
}

// The attention MLP (256->80->40->1) has NO activations => fully linear.
// logit(b,t) = sum_i [ q_i*(e_q+e_d)_i + k_i*(e_k-e_d)_i + q_i*k_i*e_p_i ] + c0
// with e = W1 @ (W2 @ Wf). This kernel computes the e-vectors and c0 once.
__global__ __launch_bounds__(128) void weff_kernel(
    const float* __restrict__ W1, const float* __restrict__ b1,
    const float* __restrict__ W2, const float* __restrict__ b2,
    const float* __restrict__ Wf, const float* __restrict__ bf,
    float* __restrict__ ws) {
    __shared__ float t80[80];
    int tid = threadIdx.x;
    if (tid < 80) {
        float s = 0.0f;
        for (int j = 0; j < 40; j++) s = fmaf(W2[tid * 40 + j], Wf[j], s);
        t80[tid] = s;
    }
    __syncthreads();
    if (tid < 64) {
        float eq = 0.f, ek = 0.f, ed = 0.f, ep = 0.f;
        for (int m = 0; m < 80; m++) {
            float t = t80[m];
            eq = fmaf(W1[tid * 80 + m],         t, eq);
            ek = fmaf(W1[(64 + tid) * 80 + m],  t, ek);
            ed = fmaf(W1[(128 + tid) * 80 + m], t, ed);
            ep = fmaf(W1[(192 + tid) * 80 + m], t, ep);
        }
        ws[tid]       = ek - ed;   // A
        ws[64 + tid]  = ep;        // P
        ws[128 + tid] = eq + ed;   // Q
    } else if (tid == 64) {
        float s = bf[0];
        for (int m = 0; m < 80; m++) s = fmaf(b1[m], t80[m], s);
        for (int j = 0; j < 40; j++) s = fmaf(b2[j], Wf[j], s);
        ws[192] = s;               // c0
    }
}

// logit per (b,t): 64-wide fused dot, HBM-bound on the single gru read.
__global__ __launch_bounds__(256) void logits_kernel(
    const float* __restrict__ gru, const float* __restrict__ targets,
    const float* __restrict__ ws, float* __restrict__ logits) {
    __shared__ float4 sA[16], sP[16], sQ[16];
    __shared__ float sc0;
    int tid = threadIdx.x;
    if (tid < 16) {
        sA[tid] = ((const float4*)ws)[tid];
        sP[tid] = ((const float4*)(ws + 64))[tid];
        sQ[tid] = ((const float4*)(ws + 128))[tid];
    }
    if (tid == 16) sc0 = ws[192];
    __syncthreads();

    int idx = blockIdx.x * 256 + tid;   // exactly B*T threads
    int b = idx / 200;
    int t = idx - b * 200;
    const float4* kp = (const float4*)(gru + ((size_t)b * 200 + t) * 64);
    const float4* qp = (const float4*)(targets + (size_t)b * 64);

    float a0 = sc0, a1 = 0.f, a2 = 0.f, a3 = 0.f;
#pragma unroll
    for (int i = 0; i < 16; i++) {
        float4 kv = kp[i], qv = qp[i], A = sA[i], P = sP[i], Q = sQ[i];
        a0 = fmaf(qv.x, Q.x, a0); a0 = fmaf(kv.x, fmaf(qv.x, P.x, A.x), a0);
        a1 = fmaf(qv.y, Q.y, a1); a1 = fmaf(kv.y, fmaf(qv.y, P.y, A.y), a1);
        a2 = fmaf(qv.z, Q.z, a2); a2 = fmaf(kv.z, fmaf(qv.z, P.z, A.z), a2);
        a3 = fmaf(qv.w, Q.w, a3); a3 = fmaf(kv.w, fmaf(qv.w, P.w, A.w), a3);
    }
    float lg = (a0 + a1) + (a2 + a3);
    if (lg == 0.0f) lg = -INFINITY;
    logits[(size_t)t * BB + b] = lg;
}

// softmax over batch dim for each t; scores stored [T][B] (coalesced)
__global__ __launch_bounds__(256) void softmax_kernel(const float* __restrict__ logits,
                                                      float* __restrict__ scores) {
    int t = blockIdx.x;
    int tid = threadIdx.x;
    const float* L = logits + (size_t)t * BB;
    float v[16];
#pragma unroll
    for (int i = 0; i < 16; i++) {
        float x = L[tid + i * 256];
        v[i] = (x == 0.0f) ? -INFINITY : x;
    }
    float m = v[0];
#pragma unroll
    for (int i = 1; i < 16; i++) m = fmaxf(m, v[i]);
#pragma unroll
    for (int off = 32; off; off >>= 1) m = fmaxf(m, __shfl_xor(m, off));
    __shared__ float sm[4];
    __shared__ float ss[4];
    int wid = tid >> 6;
    if ((tid & 63) == 0) sm[wid] = m;
    __syncthreads();
    m = fmaxf(fmaxf(sm[0], sm[1]), fmaxf(sm[2], sm[3]));
    float e[16];
    float s = 0.0f;
#pragma unroll
    for (int i = 0; i < 16; i++) {
        e[i] = __expf(v[i] - m);
        s += e[i];
    }
#pragma unroll
    for (int off = 32; off; off >>= 1) s += __shfl_xor(s, off);
    if ((tid & 63) == 0) ss[wid] = s;
    __syncthreads();
    s = ss[0] + ss[1] + ss[2] + ss[3];
    float inv = 1.0f / s;
    float* S = scores + (size_t)t * BB;
#pragma unroll
    for (int i = 0; i < 16; i++) S[tid + i * 256] = e[i] * inv;
}

// Batched x-side precompute, register-blocked to cut LDS-issue 4x vs round-4:
// 128 rows/block, thread = 4 rows x 8 cols (acc 32 regs, pk_fma).
// Each W b128 read now feeds 16 MACs (was 4). xc written in natural row
// order [n][64] (n = b*200+t) -> fully coalesced writes and streaming
// reads in augru. xg[n] = {x.Wu1, x.Wr1} also emitted here.
#define XPAD 68
__global__ __launch_bounds__(256) void xprep_kernel(
    const float* __restrict__ gru, const float* __restrict__ Wc,
    const float* __restrict__ bc, const float* __restrict__ Wu,
    const float* __restrict__ Wr, float* __restrict__ xc,
    float* __restrict__ xg) {
    __shared__ float Xs[128][XPAD];   // 34.8 KB
    __shared__ float Ws[64 * 64];     // 16 KB, Ws[k*64+j]
    const int tid = threadIdx.x;
    const int n0 = blockIdx.x * 128;

    // stage W (linear copy, 4096 floats)
    {
        const float4* Wq = (const float4*)Wc;
        float4* Wsq = (float4*)Ws;
#pragma unroll
        for (int i = 0; i < 4; i++) Wsq[tid + 256 * i] = Wq[tid + 256 * i];
    }
    // stage X: thread = half a row (32 floats)
    {
        int row = tid >> 1, half = tid & 1;
        const float4* gq = (const float4*)(gru + (size_t)(n0 + row) * 64 + half * 32);
#pragma unroll
        for (int i = 0; i < 8; i++) {
            *(float4*)&Xs[row][half * 32 + i * 4] = gq[i];
        }
    }
    __syncthreads();

    const int qs = tid & 7;    // output block: cols [qs*8, qs*8+8)
    const int g  = tid >> 3;   // group 0..31: rows {g, g+32, g+64, g+96}

    v2f acc[4][4];
    {
        const v2f* bc2 = (const v2f*)(bc + qs * 8);
        v2f b0 = bc2[0], b1 = bc2[1], b2v = bc2[2], b3 = bc2[3];
#pragma unroll
        for (int ri = 0; ri < 4; ri++) {
            acc[ri][0] = b0; acc[ri][1] = b1; acc[ri][2] = b2v; acc[ri][3] = b3;
        }
    }

#pragma unroll 4
    for (int kc = 0; kc < 16; kc++) {
        float4 xr[4];
#pragma unroll
        for (int ri = 0; ri < 4; ri++)
            xr[ri] = *(const float4*)&Xs[g + 32 * ri][kc * 4];
#pragma unroll
        for (int kk = 0; kk < 4; kk++) {
            const float4* wq = (const float4*)&Ws[(kc * 4 + kk) * 64 + qs * 8];
            float4 wa = wq[0], wb = wq[1];
            v2f w0 = {wa.x, wa.y}, w1 = {wa.z, wa.w};
            v2f w2 = {wb.x, wb.y}, w3 = {wb.z, wb.w};
#pragma unroll
            for (int ri = 0; ri < 4; ri++) {
                float xv = (kk == 0) ? xr[ri].x : (kk == 1) ? xr[ri].y
                         : (kk == 2) ? xr[ri].z : xr[ri].w;
                v2f xb = {xv, xv};
                acc[ri][0] = __builtin_elementwise_fma(xb, w0, acc[ri][0]);
                acc[ri][1] = __builtin_elementwise_fma(xb, w1, acc[ri][1]);
                acc[ri][2] = __builtin_elementwise_fma(xb, w2, acc[ri][2]);
                acc[ri][3] = __builtin_elementwise_fma(xb, w3, acc[ri][3]);
            }
        }
    }

    // write xc (row-contiguous, coalesced 256B per row across qs)
#pragma unroll
    for (int ri = 0; ri < 4; ri++) {
        int n = n0 + g + 32 * ri;
        float4 o0 = {acc[ri][0].x, acc[ri][0].y, acc[ri][1].x, acc[ri][1].y};
        float4 o1 = {acc[ri][2].x, acc[ri][2].y, acc[ri][3].x, acc[ri][3].y};
        float4* o = (float4*)(xc + (size_t)n * 64 + qs * 8);
        o[0] = o0;
        o[1] = o1;
    }

    // xg tail: thread (g,qs) computes one full 64-dot:
    //   row = g + 32*(qs&3); component = qs>>2 (0 => x.Wu1, 1 => x.Wr1)
    {
        int m = qs & 3;
        int row = g + 32 * m;
        const float* wsel = (qs >> 2) ? Wr : Wu;
        const float4* wq = (const float4*)wsel;
        float d0 = 0.f, d1 = 0.f, d2 = 0.f, d3 = 0.f;
#pragma unroll
        for (int i = 0; i < 16; i++) {
            float4 xv = *(const float4*)&Xs[row][i * 4];
            float4 wv = wq[i];
            d0 = fmaf(xv.x, wv.x, d0);
            d1 = fmaf(xv.y, wv.y, d1);
            d2 = fmaf(xv.z, wv.z, d2);
            d3 = fmaf(xv.w, wv.w, d3);
        }
        float dot = (d0 + d1) + (d2 + d3);
        int n = n0 + row;
        xg[(size_t)n * 2 + (qs >> 2)] = dot;
    }
}

// Consumer-only AUGRU v3. 4 waves/block (one b each, no barriers).
// - scores/xg preloaded to LDS once (no per-step global gathers/addr math)
// - xc read as a contiguous 256B/step stream ([b][t][64] layout), 2-deep
//   prefetch, guard-free main loop (tail peeled)
// - candidate matvec in v_pk_fma_f32 (float2 ext-vector), 32 instr
// - launch_bounds(256,1): enough VGPR budget to keep wc2 in VGPRs
__global__ __launch_bounds__(256, 1) void augru3_kernel(
    const float* __restrict__ xc, const float* __restrict__ xg,
    const float* __restrict__ scores,
    const float* __restrict__ Wu, const float* __restrict__ bu,
    const float* __restrict__ Wr, const float* __restrict__ br,
    const float* __restrict__ Wc, float* __restrict__ out) {
    __shared__ float  hbuf[4][64];
    __shared__ float  ssc[4][200];
    __shared__ float2 sxgl[4][200];
    const int lane = threadIdx.x & 63;
    const int wid  = threadIdx.x >> 6;
    const int b    = blockIdx.x * 4 + wid;

    // preload per-b scores (strided gather, L2-hot) and xg (contiguous)
    const float2* xg2 = (const float2*)xg;
    for (int t0 = lane; t0 < TT; t0 += 64) {
        ssc[wid][t0]  = scores[(size_t)t0 * BB + b];
        sxgl[wid][t0] = xg2[(size_t)b * TT + t0];
    }

    v2f wc[32];
#pragma unroll
    for (int m = 0; m < 32; m++) {
        wc[m].x = Wc[(64 + 2 * m) * 64 + lane];
        wc[m].y = Wc[(64 + 2 * m + 1) * 64 + lane];
    }
    const float wu2l = Wu[64 + lane];
    const float wr2l = Wr[64 + lane];
    const float sbu = bu[0], sbr = br[0];

    float h = 0.0f;
    float* hb = hbuf[wid];
    const float4* h4 = (const float4*)hb;
    const float* ssw = ssc[wid];
    const float2* sxw = sxgl[wid];

    auto step = [&](int t, float xl) {
        hb[lane] = h;
        float pu = wave_sum64(h * wu2l);
        float pr = wave_sum64(h * wr2l);
        float sc = ssw[t];
        float2 gg = sxw[t];
        float u = sc / (1.0f + __expf(-(pu + gg.x + sbu)));
        float r = 1.0f / (1.0f + __expf(-(pr + gg.y + sbr)));

        v2f a0 = {0.f, 0.f}, a1 = a0, a2 = a0, a3 = a0;
#pragma unroll
        for (int q = 0; q < 16; q += 2) {
            float4 hA = h4[q], hB = h4[q + 1];
            v2f hA0 = {hA.x, hA.y}, hA1 = {hA.z, hA.w};
            v2f hB0 = {hB.x, hB.y}, hB1 = {hB.z, hB.w};
            a0 = __builtin_elementwise_fma(hA0, wc[2 * q],     a0);
            a1 = __builtin_elementwise_fma(hA1, wc[2 * q + 1], a1);
            a2 = __builtin_elementwise_fma(hB0, wc[2 * q + 2], a2);
            a3 = __builtin_elementwise_fma(hB1, wc[2 * q + 3], a3);
        }
        v2f sv = (a0 + a1) + (a2 + a3);
        float cand = sv.x + sv.y;

        float arg = xl + r * cand;
        float ex = __expf(2.0f * arg);   // tanh
        float th = 1.0f - 2.0f / (ex + 1.0f);
        h = fmaf(u, th - h, h);
    };

    const float* xp = xc + (size_t)b * TT * 64 + lane;
    float x0 = xp[0];
    float x1 = xp[64];
    for (int t = 0; t < TT - 2; t++) {
        float x2 = xp[128];
        xp += 64;
        step(t, x0);
        x0 = x1; x1 = x2;
    }
    step(TT - 2, x0);
    step(TT - 1, x1);

    out[(size_t)b * 64 + lane] = h;
}

// ---- fallback (small workspace): original fused producer/consumer AUGRU ----
__global__ __launch_bounds__(128, 4) void augru_kernel(
    const float* __restrict__ gru, const float* __restrict__ scores,
    const float* __restrict__ Wu, const float* __restrict__ bu,
    const float* __restrict__ Wr, const float* __restrict__ br,
    const float* __restrict__ Wc, const float* __restrict__ bc,
    float* __restrict__ out) {
    __shared__ float sxc[2][64];
    __shared__ float sxg[2][2];
    const int lane = threadIdx.x & 63;
    const int wid  = threadIdx.x >> 6;
    const int b    = blockIdx.x;
    const float* xrow = gru + (size_t)b * TT * 64;

    if (wid == 0) {
        float wc1[64];
#pragma unroll
        for (int k = 0; k < 64; k++) wc1[k] = Wc[k * 64 + lane];
        float wu1l = Wu[lane], wr1l = Wr[lane];
        float bcl = bc[lane];

        auto produce = [&](int tp, float xl) {
            float pu = xl * wu1l;
            float pr = xl * wr1l;
#pragma unroll
            for (int off = 32; off; off >>= 1) {
                pu += __shfl_xor(pu, off);
                pr += __shfl_xor(pr, off);
            }
            float a0 = bcl, a1 = 0.0f, a2 = 0.0f, a3 = 0.0f;
#pragma unroll
            for (int k = 0; k < 16; k++) {
                a0 = fmaf(lane_bcast(xl, 4 * k + 0), wc1[4 * k + 0], a0);
                a1 = fmaf(lane_bcast(xl, 4 * k + 1), wc1[4 * k + 1], a1);
                a2 = fmaf(lane_bcast(xl, 4 * k + 2), wc1[4 * k + 2], a2);
                a3 = fmaf(lane_bcast(xl, 4 * k + 3), wc1[4 * k + 3], a3);
            }
            int p = tp & 1;
            sxc[p][lane] = (a0 + a1) + (a2 + a3);
            if (lane == 0) sxg[p][0] = pu;
            if (lane == 1) sxg[p][1] = pr;
        };

        float xl = xrow[lane];
        float xn = xrow[64 + lane];
        produce(0, xl);
        xl = xn;
        __syncthreads();
        for (int t = 0; t < TT; t++) {
            if (t + 1 < TT) {
                float xnn = (t + 2 < TT) ? xrow[(size_t)(t + 2) * 64 + lane] : 0.0f;
                produce(t + 1, xl);
                xl = xnn;
            }
            __syncthreads();
        }
    } else {
        float wc2[64];
#pragma unroll
        for (int k = 0; k < 64; k++) wc2[k] = Wc[(64 + k) * 64 + lane];
        float wu2l = Wu[64 + lane], wr2l = Wr[64 + lane];
        float sbu = bu[0], sbr = br[0];
        float h = 0.0f;
        __syncthreads();
        for (int t = 0; t < TT; t++) {
            int p = t & 1;
            float sc = scores[(size_t)t * BB + b];
            float xcv = sxc[p][lane];
            float xu = sxg[p][0];
            float xv = sxg[p][1];
            float pu = h * wu2l;
            float pr = h * wr2l;
#pragma unroll
            for (int off = 32; off; off >>= 1) {
                pu += __shfl_xor(pu, off);
                pr += __shfl_xor(pr, off);
            }
            float u = sc / (1.0f + __expf(-(pu + xu + sbu)));
            float r = 1.0f / (1.0f + __expf(-(pr + xv + sbr)));
            float a0 = 0.0f, a1 = 0.0f, a2 = 0.0f, a3 = 0.0f;
#pragma unroll
            for (int k = 0; k < 16; k++) {
                a0 = fmaf(lane_bcast(h, 4 * k + 0), wc2[4 * k + 0], a0);
                a1 = fmaf(lane_bcast(h, 4 * k + 1), wc2[4 * k + 1], a1);
                a2 = fmaf(lane_bcast(h, 4 * k + 2), wc2[4 * k + 2], a2);
                a3 = fmaf(lane_bcast(h, 4 * k + 3), wc2[4 * k + 3], a3);
            }
            float arg = xcv + r * ((a0 + a1) + (a2 + a3));
            float ex = __expf(2.0f * arg);
            float th = 1.0f - 2.0f / (ex + 1.0f);
            h = fmaf(u, th - h, h);
            __syncthreads();
        }
        out[(size_t)b * 64 + lane] = h;
    }
}

extern "C" void kernel_launch(void* const* d_in, const int* in_sizes, int n_in,
                              void* d_out, int out_size, void* d_ws, size_t ws_size,
                              hipStream_t stream) {
    const float* gru     = (const float*)d_in[0];
    const float* targets = (const float*)d_in[1];
    const float* W1 = (const float*)d_in[2];
    const float* b1 = (const float*)d_in[3];
    const float* W2 = (const float*)d_in[4];
    const float* b2 = (const float*)d_in[5];
    const float* Wf = (const float*)d_in[6];
    const float* bf = (const float*)d_in[7];
    const float* Wu = (const float*)d_in[8];
    const float* bu = (const float*)d_in[9];
    const float* Wr = (const float*)d_in[10];
    const float* br = (const float*)d_in[11];
    const float* Wc = (const float*)d_in[12];
    const float* bc = (const float*)d_in[13];
    float* out = (float*)d_out;

    float* ws     = (float*)d_ws;
    float* logits = ws + 337920;
    float* scores = ws + 1157120;

    const bool big = (ws_size >= WS_NEED_BYTES);
    float* xg = ws + OFF_XG;
    float* xc = ws + OFF_XC;

    weff_kernel<<<1, 128, 0, stream>>>(W1, b1, W2, b2, Wf, bf, ws);
    logits_kernel<<<3200, 256, 0, stream>>>(gru, targets, ws, logits);
    softmax_kernel<<<200, 256, 0, stream>>>(logits, scores);
    if (big) {
        xprep_kernel<<<6400, 256, 0, stream>>>(gru, Wc, bc, Wu, Wr, xc, xg);
        augru3_kernel<<<1024, 256, 0, stream>>>(xc, xg, scores, Wu, bu, Wr, br, Wc, out);
    } else {
        augru_kernel<<<4096, 128, 0, stream>>>(gru, scores, Wu, bu, Wr, br, Wc, bc, out);
    }
}